// Round 1
// baseline (389.182 us; speedup 1.0000x reference)
//
#include <hip/hip_runtime.h>

constexpr int B_ = 2, N_ = 2048, C_ = 1024, H_ = 16, HD_ = 64, FF_ = 2048;

typedef __attribute__((ext_vector_type(8))) __bf16 bf16x8;
typedef __attribute__((ext_vector_type(4))) float f32x4;
typedef __attribute__((ext_vector_type(4))) short s16x4;

__device__ __forceinline__ unsigned short f2bf(float f) {
  union { float f; unsigned int u; } v; v.f = f;
  unsigned int r = v.u + 0x7fffu + ((v.u >> 16) & 1u);
  return (unsigned short)(r >> 16);
}

__device__ __forceinline__ void gload_lds16(const unsigned short* g, unsigned short* l) {
  __builtin_amdgcn_global_load_lds((const __attribute__((address_space(1))) void*)g,
                                   (__attribute__((address_space(3))) void*)l, 16, 0, 0);
}

// ---------------- cast f32 -> bf16 (8 elems/thread) ----------------
__global__ __launch_bounds__(256)
void cast_bf16(const float* __restrict__ in, unsigned short* __restrict__ out, int n8) {
  int i = blockIdx.x * 256 + threadIdx.x;
  if (i >= n8) return;
  const float4 a = ((const float4*)in)[2 * i];
  const float4 b = ((const float4*)in)[2 * i + 1];
  uint4 o;
  o.x = (unsigned)f2bf(a.x) | ((unsigned)f2bf(a.y) << 16);
  o.y = (unsigned)f2bf(a.z) | ((unsigned)f2bf(a.w) << 16);
  o.z = (unsigned)f2bf(b.x) | ((unsigned)f2bf(b.y) << 16);
  o.w = (unsigned)f2bf(b.z) | ((unsigned)f2bf(b.w) << 16);
  ((uint4*)out)[i] = o;
}

// ---------------- cast+transpose weights: W[K][N] f32 -> Wt[N][K] bf16 ----------------
__global__ __launch_bounds__(256)
void wt_cast(const float* __restrict__ W, unsigned short* __restrict__ Wt, int K, int N) {
  __shared__ unsigned short tile[32][33];
  const int tx = threadIdx.x, ty = threadIdx.y;
  const int n0 = blockIdx.x * 32, k0 = blockIdx.y * 32;
#pragma unroll
  for (int r = 0; r < 4; ++r)
    tile[ty + r * 8][tx] = f2bf(W[(size_t)(k0 + ty + r * 8) * N + n0 + tx]);
  __syncthreads();
#pragma unroll
  for (int r = 0; r < 4; ++r)
    Wt[(size_t)(n0 + ty + r * 8) * K + k0 + tx] = tile[tx][ty + r * 8];
}

// ---------------- Vh [B,N,H,HD] -> VhT [B,H,HD,N] (bf16) ----------------
__global__ __launch_bounds__(256)
void vh_transpose(const unsigned short* __restrict__ Vh, unsigned short* __restrict__ VhT) {
  __shared__ unsigned short tile[32][33];
  const int tx = threadIdx.x, ty = threadIdx.y;
  const int bh = blockIdx.z, b = bh >> 4, h = bh & 15;
  const int n0 = blockIdx.x * 32, d0 = blockIdx.y * 32;
#pragma unroll
  for (int r = 0; r < 4; ++r) {
    int n = n0 + ty + r * 8;
    tile[ty + r * 8][tx] = Vh[((size_t)(b * N_ + n)) * C_ + h * HD_ + d0 + tx];
  }
  __syncthreads();
#pragma unroll
  for (int r = 0; r < 4; ++r) {
    int d = d0 + ty + r * 8;
    VhT[((size_t)(bh * HD_ + d)) * N_ + n0 + tx] = tile[tx][ty + r * 8];
  }
}

// ---------------- GEMM: C[M,N] = A[M,K](bf16) * Bt[N,K]^T(bf16) + bias, epilogues ----------------
// EPI 0: out_bf16 = v + bias
// EPI 1: out_f32  = v + bias + resid
// EPI 2: out_bf16 = gelu_exact(v + bias)
template <int EPI>
__global__ __launch_bounds__(256, 2)
void gemm_bt(const unsigned short* __restrict__ A, const unsigned short* __restrict__ Bt,
             const float* __restrict__ bias, const float* __restrict__ resid,
             float* __restrict__ outF, unsigned short* __restrict__ outB,
             int M, int N, int K) {
  __shared__ unsigned short lA[128 * 64];
  __shared__ unsigned short lB[128 * 64];
  const int t = threadIdx.x;
  const int lane = t & 63;
  const int w = t >> 6;
  const int wm = w >> 1, wn = w & 1;
  const int l15 = lane & 15, g = lane >> 4;

  const unsigned short* Ab = A + (size_t)blockIdx.x * 128 * K;
  const unsigned short* Bb = Bt + (size_t)blockIdx.y * 128 * K;

  f32x4 acc[4][4] = {};

  for (int k0 = 0; k0 < K; k0 += 64) {
    __syncthreads();
#pragma unroll
    for (int i = 0; i < 4; ++i) {
      int id = i * 256 + t;
      gload_lds16(Ab + (size_t)(id >> 3) * K + k0 + (id & 7) * 8, &lA[id * 8]);
    }
#pragma unroll
    for (int i = 0; i < 4; ++i) {
      int id = i * 256 + t;
      gload_lds16(Bb + (size_t)(id >> 3) * K + k0 + (id & 7) * 8, &lB[id * 8]);
    }
    __syncthreads();
#pragma unroll
    for (int kk = 0; kk < 2; ++kk) {
      bf16x8 af[4], bfr[4];
#pragma unroll
      for (int mi = 0; mi < 4; ++mi)
        af[mi] = *(const bf16x8*)&lA[(wm * 64 + mi * 16 + l15) * 64 + kk * 32 + g * 8];
#pragma unroll
      for (int ni = 0; ni < 4; ++ni)
        bfr[ni] = *(const bf16x8*)&lB[(wn * 64 + ni * 16 + l15) * 64 + kk * 32 + g * 8];
#pragma unroll
      for (int mi = 0; mi < 4; ++mi)
#pragma unroll
        for (int ni = 0; ni < 4; ++ni)
          acc[mi][ni] = __builtin_amdgcn_mfma_f32_16x16x32_bf16(af[mi], bfr[ni], acc[mi][ni], 0, 0, 0);
    }
  }

#pragma unroll
  for (int mi = 0; mi < 4; ++mi)
#pragma unroll
    for (int ni = 0; ni < 4; ++ni) {
      const int col = blockIdx.y * 128 + wn * 64 + ni * 16 + l15;
      const float bcol = bias[col];
#pragma unroll
      for (int r = 0; r < 4; ++r) {
        const int row = blockIdx.x * 128 + wm * 64 + mi * 16 + g * 4 + r;
        const size_t o = (size_t)row * N + col;
        float val = acc[mi][ni][r] + bcol;
        if (EPI == 0) {
          outB[o] = f2bf(val);
        } else if (EPI == 1) {
          outF[o] = val + resid[o];
        } else {
          float ge = 0.5f * val * (1.0f + erff(val * 0.70710678118654752f));
          outB[o] = f2bf(ge);
        }
      }
    }
}

// ---------------- flash attention ----------------
// grid: (N/128, B*H), 256 threads = 4 waves, 32 q-rows per wave.
// Swapped QK^T: S^T = mfma(K_frag, Q_frag) -> lane holds P[k=4g+reg][q=l15].
// PV: O^T = mfma_16x16x16(V^T_frag, P_frag) -> lane holds O^T[d=4g+reg][q=l15].
__global__ __launch_bounds__(256, 2)
void attn_fwd(const unsigned short* __restrict__ Qh, const unsigned short* __restrict__ Kh,
              const unsigned short* __restrict__ VhT, unsigned short* __restrict__ ctx) {
  const int t = threadIdx.x, lane = t & 63, w = t >> 6;
  const int l15 = lane & 15, g = lane >> 4;
  const int bh = blockIdx.y, b = bh >> 4, h = bh & 15;
  const int qb0 = blockIdx.x * 128 + w * 32;

  const unsigned short* Qb = Qh + (size_t)b * N_ * C_ + h * HD_;
  const unsigned short* Kb = Kh + (size_t)b * N_ * C_ + h * HD_;
  const unsigned short* Vb = VhT + (size_t)bh * HD_ * N_;

  bf16x8 qf[2][2];
#pragma unroll
  for (int qi = 0; qi < 2; ++qi)
#pragma unroll
    for (int kk = 0; kk < 2; ++kk)
      qf[qi][kk] = *(const bf16x8*)(Qb + (size_t)(qb0 + qi * 16 + l15) * C_ + kk * 32 + g * 8);

  f32x4 od[4][2] = {};
  float mrun[2] = {-1e30f, -1e30f};
  float srun[2] = {0.f, 0.f};
  const float c1 = 0.18033688011112042f;  // 1/sqrt(64) * log2(e)

  for (int kb = 0; kb < N_; kb += 32) {
    bf16x8 kfr[2][2];
#pragma unroll
    for (int kf = 0; kf < 2; ++kf)
#pragma unroll
      for (int kk = 0; kk < 2; ++kk)
        kfr[kf][kk] = *(const bf16x8*)(Kb + (size_t)(kb + kf * 16 + l15) * C_ + kk * 32 + g * 8);

    f32x4 st[2][2];
#pragma unroll
    for (int kf = 0; kf < 2; ++kf)
#pragma unroll
      for (int qi = 0; qi < 2; ++qi) {
        f32x4 z = {};
        z = __builtin_amdgcn_mfma_f32_16x16x32_bf16(kfr[kf][0], qf[qi][0], z, 0, 0, 0);
        z = __builtin_amdgcn_mfma_f32_16x16x32_bf16(kfr[kf][1], qf[qi][1], z, 0, 0, 0);
        st[kf][qi] = z;
      }

    // online softmax (q = l15 is lane-local; k spans regs + lane-groups)
#pragma unroll
    for (int qi = 0; qi < 2; ++qi) {
      float mx = st[0][qi][0];
#pragma unroll
      for (int r = 1; r < 4; ++r) mx = fmaxf(mx, st[0][qi][r]);
#pragma unroll
      for (int r = 0; r < 4; ++r) mx = fmaxf(mx, st[1][qi][r]);
      mx = fmaxf(mx, __shfl_xor(mx, 16));
      mx = fmaxf(mx, __shfl_xor(mx, 32));
      float mn = fmaxf(mrun[qi], mx);
      float sf = exp2f((mrun[qi] - mn) * c1);
      mrun[qi] = mn;
      srun[qi] *= sf;
#pragma unroll
      for (int di = 0; di < 4; ++di)
#pragma unroll
        for (int r = 0; r < 4; ++r) od[di][qi][r] *= sf;
    }

    s16x4 pb[2][2];
#pragma unroll
    for (int kf = 0; kf < 2; ++kf)
#pragma unroll
      for (int qi = 0; qi < 2; ++qi)
#pragma unroll
        for (int r = 0; r < 4; ++r) {
          float pv = exp2f((st[kf][qi][r] - mrun[qi]) * c1);
          srun[qi] += pv;
          pb[kf][qi][r] = (short)f2bf(pv);
        }

#pragma unroll
    for (int di = 0; di < 4; ++di)
#pragma unroll
      for (int kf = 0; kf < 2; ++kf) {
        s16x4 vt = *(const s16x4*)(Vb + (size_t)(di * 16 + l15) * N_ + kb + kf * 16 + g * 4);
#pragma unroll
        for (int qi = 0; qi < 2; ++qi)
          od[di][qi] = __builtin_amdgcn_mfma_f32_16x16x16bf16_1k(vt, pb[kf][qi], od[di][qi], 0, 0, 0);
      }
  }

#pragma unroll
  for (int qi = 0; qi < 2; ++qi) {
    float s = srun[qi];
    s += __shfl_xor(s, 16);
    s += __shfl_xor(s, 32);
    float rinv = 1.0f / s;
    const int q = qb0 + qi * 16 + l15;
#pragma unroll
    for (int di = 0; di < 4; ++di)
#pragma unroll
      for (int r = 0; r < 4; ++r) {
        int d = di * 16 + g * 4 + r;
        ctx[((size_t)(b * N_ + q)) * C_ + h * HD_ + d] = f2bf(od[di][qi][r] * rinv);
      }
  }
}

// ---------------- LayerNorm: x f32 [BN, C] -> h bf16 ----------------
__global__ __launch_bounds__(256)
void ln_kernel(const float* __restrict__ x, const float* __restrict__ lw,
               const float* __restrict__ lb, unsigned short* __restrict__ h) {
  const int row = blockIdx.x;
  const int t = threadIdx.x;
  const float4 v = ((const float4*)(x + (size_t)row * C_))[t];
  float sum = v.x + v.y + v.z + v.w;
#pragma unroll
  for (int m = 1; m < 64; m <<= 1) sum += __shfl_xor(sum, m);
  __shared__ float red[8];
  if ((t & 63) == 0) red[t >> 6] = sum;
  __syncthreads();
  const float mu = (red[0] + red[1] + red[2] + red[3]) * (1.0f / C_);
  const float d0 = v.x - mu, d1 = v.y - mu, d2 = v.z - mu, d3 = v.w - mu;
  float sq = d0 * d0 + d1 * d1 + d2 * d2 + d3 * d3;
#pragma unroll
  for (int m = 1; m < 64; m <<= 1) sq += __shfl_xor(sq, m);
  if ((t & 63) == 0) red[4 + (t >> 6)] = sq;
  __syncthreads();
  const float var = (red[4] + red[5] + red[6] + red[7]) * (1.0f / C_);
  const float rstd = rsqrtf(var + 1e-5f);
  const float4 ww = ((const float4*)lw)[t];
  const float4 bb = ((const float4*)lb)[t];
  uint2 o;
  o.x = (unsigned)f2bf(d0 * rstd * ww.x + bb.x) | ((unsigned)f2bf(d1 * rstd * ww.y + bb.y) << 16);
  o.y = (unsigned)f2bf(d2 * rstd * ww.z + bb.z) | ((unsigned)f2bf(d3 * rstd * ww.w + bb.w) << 16);
  ((uint2*)(h + (size_t)row * C_))[t] = o;
}

extern "C" void kernel_launch(void* const* d_in, const int* in_sizes, int n_in,
                              void* d_out, int out_size, void* d_ws, size_t ws_size,
                              hipStream_t stream) {
  const float* q   = (const float*)d_in[0];
  const float* k   = (const float*)d_in[1];
  const float* v   = (const float*)d_in[2];
  const float* Wq  = (const float*)d_in[3];
  const float* bq  = (const float*)d_in[4];
  const float* Wk  = (const float*)d_in[5];
  const float* bk  = (const float*)d_in[6];
  const float* Wv  = (const float*)d_in[7];
  const float* bv  = (const float*)d_in[8];
  const float* Wo  = (const float*)d_in[9];
  const float* bo  = (const float*)d_in[10];
  const float* lnw = (const float*)d_in[11];
  const float* lnb = (const float*)d_in[12];
  const float* W1  = (const float*)d_in[13];
  const float* b1  = (const float*)d_in[14];
  const float* W2  = (const float*)d_in[15];
  const float* b2  = (const float*)d_in[16];
  float* out = (float*)d_out;

  char* ws = (char*)d_ws;
  const size_t MB = 1024 * 1024;
  if (ws_size < 120 * MB) return;
  unsigned short* qb   = (unsigned short*)(ws + 0 * MB);
  unsigned short* kb   = (unsigned short*)(ws + 8 * MB);
  unsigned short* vb   = (unsigned short*)(ws + 16 * MB);
  unsigned short* Wqt  = (unsigned short*)(ws + 24 * MB);
  unsigned short* Wkt  = (unsigned short*)(ws + 26 * MB);
  unsigned short* Wvt  = (unsigned short*)(ws + 28 * MB);
  unsigned short* Wot  = (unsigned short*)(ws + 30 * MB);
  unsigned short* W1t  = (unsigned short*)(ws + 32 * MB);
  unsigned short* W2t  = (unsigned short*)(ws + 36 * MB);
  unsigned short* Qh   = (unsigned short*)(ws + 40 * MB);
  unsigned short* Kh   = (unsigned short*)(ws + 48 * MB);
  unsigned short* Vh   = (unsigned short*)(ws + 56 * MB);
  unsigned short* VhT  = (unsigned short*)(ws + 64 * MB);
  unsigned short* ctx  = (unsigned short*)(ws + 72 * MB);
  float*          xf   = (float*)(ws + 80 * MB);
  unsigned short* hb   = (unsigned short*)(ws + 96 * MB);
  unsigned short* tbuf = (unsigned short*)(ws + 104 * MB);

  const int n8 = B_ * N_ * C_ / 8;
  cast_bf16<<<dim3((n8 + 255) / 256), 256, 0, stream>>>(q, qb, n8);
  cast_bf16<<<dim3((n8 + 255) / 256), 256, 0, stream>>>(k, kb, n8);
  cast_bf16<<<dim3((n8 + 255) / 256), 256, 0, stream>>>(v, vb, n8);

  dim3 blk32(32, 8);
  wt_cast<<<dim3(C_ / 32, C_ / 32), blk32, 0, stream>>>(Wq, Wqt, C_, C_);
  wt_cast<<<dim3(C_ / 32, C_ / 32), blk32, 0, stream>>>(Wk, Wkt, C_, C_);
  wt_cast<<<dim3(C_ / 32, C_ / 32), blk32, 0, stream>>>(Wv, Wvt, C_, C_);
  wt_cast<<<dim3(C_ / 32, C_ / 32), blk32, 0, stream>>>(Wo, Wot, C_, C_);
  wt_cast<<<dim3(FF_ / 32, C_ / 32), blk32, 0, stream>>>(W1, W1t, C_, FF_);
  wt_cast<<<dim3(C_ / 32, FF_ / 32), blk32, 0, stream>>>(W2, W2t, FF_, C_);

  dim3 g1(B_ * N_ / 128, C_ / 128);
  gemm_bt<0><<<g1, 256, 0, stream>>>(qb, Wqt, bq, nullptr, nullptr, Qh, B_ * N_, C_, C_);
  gemm_bt<0><<<g1, 256, 0, stream>>>(kb, Wkt, bk, nullptr, nullptr, Kh, B_ * N_, C_, C_);
  gemm_bt<0><<<g1, 256, 0, stream>>>(vb, Wvt, bv, nullptr, nullptr, Vh, B_ * N_, C_, C_);

  vh_transpose<<<dim3(N_ / 32, HD_ / 32, B_ * H_), blk32, 0, stream>>>(Vh, VhT);
  attn_fwd<<<dim3(N_ / 128, B_ * H_), 256, 0, stream>>>(Qh, Kh, VhT, ctx);

  gemm_bt<1><<<g1, 256, 0, stream>>>(ctx, Wot, bo, q, xf, nullptr, B_ * N_, C_, C_);
  ln_kernel<<<dim3(B_ * N_), 256, 0, stream>>>(xf, lnw, lnb, hb);
  gemm_bt<2><<<dim3(B_ * N_ / 128, FF_ / 128), 256, 0, stream>>>(hb, W1t, b1, nullptr, nullptr, tbuf,
                                                                 B_ * N_, FF_, C_);
  gemm_bt<1><<<dim3(B_ * N_ / 128, C_ / 128), 256, 0, stream>>>(tbuf, W2t, b2, xf, out, nullptr,
                                                                B_ * N_, C_, FF_);
}

// Round 2
// 245.344 us; speedup vs baseline: 1.5863x; 1.5863x over previous
//
#include <hip/hip_runtime.h>

constexpr int B_ = 2, N_ = 2048, C_ = 1024, H_ = 16, HD_ = 64, FF_ = 2048;

typedef __attribute__((ext_vector_type(8))) __bf16 bf16x8;
typedef __attribute__((ext_vector_type(4))) float f32x4;
typedef __attribute__((ext_vector_type(4))) short s16x4;

__device__ __forceinline__ unsigned short f2bf(float f) {
  union { float f; unsigned int u; } v; v.f = f;
  unsigned int r = v.u + 0x7fffu + ((v.u >> 16) & 1u);
  return (unsigned short)(r >> 16);
}

__device__ __forceinline__ void gload_lds16(const unsigned short* g, unsigned short* l) {
  __builtin_amdgcn_global_load_lds((const __attribute__((address_space(1))) void*)g,
                                   (__attribute__((address_space(3))) void*)l, 16, 0, 0);
}

// ---------------- cast f32 -> bf16, z-fused over q,k,v ----------------
__global__ __launch_bounds__(256)
void cast3_bf16(const float* __restrict__ q, const float* __restrict__ k,
                const float* __restrict__ v, unsigned short* __restrict__ qo,
                unsigned short* __restrict__ ko, unsigned short* __restrict__ vo, int n8) {
  int i = blockIdx.x * 256 + threadIdx.x;
  if (i >= n8) return;
  const float* in = blockIdx.z == 0 ? q : (blockIdx.z == 1 ? k : v);
  unsigned short* out = blockIdx.z == 0 ? qo : (blockIdx.z == 1 ? ko : vo);
  const float4 a = ((const float4*)in)[2 * i];
  const float4 b = ((const float4*)in)[2 * i + 1];
  uint4 o;
  o.x = (unsigned)f2bf(a.x) | ((unsigned)f2bf(a.y) << 16);
  o.y = (unsigned)f2bf(a.z) | ((unsigned)f2bf(a.w) << 16);
  o.z = (unsigned)f2bf(b.x) | ((unsigned)f2bf(b.y) << 16);
  o.w = (unsigned)f2bf(b.z) | ((unsigned)f2bf(b.w) << 16);
  ((uint4*)out)[i] = o;
}

// ---------------- cast+transpose weights: W[K][N] f32 -> Wt[N][K] bf16 ----------------
__global__ __launch_bounds__(256)
void wt_cast(const float* __restrict__ W, unsigned short* __restrict__ Wt, int K, int N) {
  __shared__ unsigned short tile[32][33];
  const int tx = threadIdx.x, ty = threadIdx.y;
  const int n0 = blockIdx.x * 32, k0 = blockIdx.y * 32;
#pragma unroll
  for (int r = 0; r < 4; ++r)
    tile[ty + r * 8][tx] = f2bf(W[(size_t)(k0 + ty + r * 8) * N + n0 + tx]);
  __syncthreads();
#pragma unroll
  for (int r = 0; r < 4; ++r)
    Wt[(size_t)(n0 + ty + r * 8) * K + k0 + tx] = tile[tx][ty + r * 8];
}

// z-fused version for the four C x C weights
__global__ __launch_bounds__(256)
void wt_cast4(const float* __restrict__ Wa, const float* __restrict__ Wb,
              const float* __restrict__ Wc, const float* __restrict__ Wd,
              unsigned short* __restrict__ Oa, unsigned short* __restrict__ Ob,
              unsigned short* __restrict__ Oc, unsigned short* __restrict__ Od) {
  __shared__ unsigned short tile[32][33];
  const int z = blockIdx.z;
  const float* W = z == 0 ? Wa : (z == 1 ? Wb : (z == 2 ? Wc : Wd));
  unsigned short* Wt = z == 0 ? Oa : (z == 1 ? Ob : (z == 2 ? Oc : Od));
  const int tx = threadIdx.x, ty = threadIdx.y;
  const int n0 = blockIdx.x * 32, k0 = blockIdx.y * 32;
#pragma unroll
  for (int r = 0; r < 4; ++r)
    tile[ty + r * 8][tx] = f2bf(W[(size_t)(k0 + ty + r * 8) * C_ + n0 + tx]);
  __syncthreads();
#pragma unroll
  for (int r = 0; r < 4; ++r)
    Wt[(size_t)(n0 + ty + r * 8) * C_ + k0 + tx] = tile[tx][ty + r * 8];
}

// ---------------- Vh [B,N,H,HD] -> VhT [B,H,HD,N] (bf16) ----------------
__global__ __launch_bounds__(256)
void vh_transpose(const unsigned short* __restrict__ Vh, unsigned short* __restrict__ VhT) {
  __shared__ unsigned short tile[32][33];
  const int tx = threadIdx.x, ty = threadIdx.y;
  const int bh = blockIdx.z, b = bh >> 4, h = bh & 15;
  const int n0 = blockIdx.x * 32, d0 = blockIdx.y * 32;
#pragma unroll
  for (int r = 0; r < 4; ++r) {
    int n = n0 + ty + r * 8;
    tile[ty + r * 8][tx] = Vh[((size_t)(b * N_ + n)) * C_ + h * HD_ + d0 + tx];
  }
  __syncthreads();
#pragma unroll
  for (int r = 0; r < 4; ++r) {
    int d = d0 + ty + r * 8;
    VhT[((size_t)(bh * HD_ + d)) * N_ + n0 + tx] = tile[tx][ty + r * 8];
  }
}

// ---------------- 128x128 GEMM, z-fused QKV projections (out bf16 = v+bias) ----------------
__global__ __launch_bounds__(256, 2)
void gemm_qkv(const unsigned short* __restrict__ A0, const unsigned short* __restrict__ A1,
              const unsigned short* __restrict__ A2, const unsigned short* __restrict__ B0,
              const unsigned short* __restrict__ B1, const unsigned short* __restrict__ B2,
              const float* __restrict__ c0, const float* __restrict__ c1v,
              const float* __restrict__ c2, unsigned short* __restrict__ O0,
              unsigned short* __restrict__ O1, unsigned short* __restrict__ O2) {
  const int z = blockIdx.z;
  const unsigned short* A = z == 0 ? A0 : (z == 1 ? A1 : A2);
  const unsigned short* Bt = z == 0 ? B0 : (z == 1 ? B1 : B2);
  const float* bias = z == 0 ? c0 : (z == 1 ? c1v : c2);
  unsigned short* outB = z == 0 ? O0 : (z == 1 ? O1 : O2);
  const int K = C_, Nn = C_;

  __shared__ unsigned short lA[128 * 64];
  __shared__ unsigned short lB[128 * 64];
  const int t = threadIdx.x;
  const int lane = t & 63;
  const int w = t >> 6;
  const int wm = w >> 1, wn = w & 1;
  const int l15 = lane & 15, g = lane >> 4;

  const unsigned short* Ab = A + (size_t)blockIdx.x * 128 * K;
  const unsigned short* Bb = Bt + (size_t)blockIdx.y * 128 * K;

  f32x4 acc[4][4] = {};

  for (int k0 = 0; k0 < K; k0 += 64) {
    __syncthreads();
#pragma unroll
    for (int i = 0; i < 4; ++i) {
      int id = i * 256 + t;
      gload_lds16(Ab + (size_t)(id >> 3) * K + k0 + (id & 7) * 8, &lA[id * 8]);
    }
#pragma unroll
    for (int i = 0; i < 4; ++i) {
      int id = i * 256 + t;
      gload_lds16(Bb + (size_t)(id >> 3) * K + k0 + (id & 7) * 8, &lB[id * 8]);
    }
    __syncthreads();
#pragma unroll
    for (int kk = 0; kk < 2; ++kk) {
      bf16x8 af[4], bfr[4];
#pragma unroll
      for (int mi = 0; mi < 4; ++mi)
        af[mi] = *(const bf16x8*)&lA[(wm * 64 + mi * 16 + l15) * 64 + kk * 32 + g * 8];
#pragma unroll
      for (int ni = 0; ni < 4; ++ni)
        bfr[ni] = *(const bf16x8*)&lB[(wn * 64 + ni * 16 + l15) * 64 + kk * 32 + g * 8];
#pragma unroll
      for (int mi = 0; mi < 4; ++mi)
#pragma unroll
        for (int ni = 0; ni < 4; ++ni)
          acc[mi][ni] = __builtin_amdgcn_mfma_f32_16x16x32_bf16(af[mi], bfr[ni], acc[mi][ni], 0, 0, 0);
    }
  }

#pragma unroll
  for (int mi = 0; mi < 4; ++mi)
#pragma unroll
    for (int ni = 0; ni < 4; ++ni) {
      const int col = blockIdx.y * 128 + wn * 64 + ni * 16 + l15;
      const float bcol = bias[col];
#pragma unroll
      for (int r = 0; r < 4; ++r) {
        const int row = blockIdx.x * 128 + wm * 64 + mi * 16 + g * 4 + r;
        outB[(size_t)row * Nn + col] = f2bf(acc[mi][ni][r] + bcol);
      }
    }
}

// ---------------- 128x128 GEMM with epilogues (used for FFN-up, gelu) ----------------
// EPI 2: out_bf16 = gelu_exact(v + bias)
template <int EPI>
__global__ __launch_bounds__(256, 2)
void gemm_bt(const unsigned short* __restrict__ A, const unsigned short* __restrict__ Bt,
             const float* __restrict__ bias, const float* __restrict__ resid,
             float* __restrict__ outF, unsigned short* __restrict__ outB,
             int M, int N, int K) {
  __shared__ unsigned short lA[128 * 64];
  __shared__ unsigned short lB[128 * 64];
  const int t = threadIdx.x;
  const int lane = t & 63;
  const int w = t >> 6;
  const int wm = w >> 1, wn = w & 1;
  const int l15 = lane & 15, g = lane >> 4;

  const unsigned short* Ab = A + (size_t)blockIdx.x * 128 * K;
  const unsigned short* Bb = Bt + (size_t)blockIdx.y * 128 * K;

  f32x4 acc[4][4] = {};

  for (int k0 = 0; k0 < K; k0 += 64) {
    __syncthreads();
#pragma unroll
    for (int i = 0; i < 4; ++i) {
      int id = i * 256 + t;
      gload_lds16(Ab + (size_t)(id >> 3) * K + k0 + (id & 7) * 8, &lA[id * 8]);
    }
#pragma unroll
    for (int i = 0; i < 4; ++i) {
      int id = i * 256 + t;
      gload_lds16(Bb + (size_t)(id >> 3) * K + k0 + (id & 7) * 8, &lB[id * 8]);
    }
    __syncthreads();
#pragma unroll
    for (int kk = 0; kk < 2; ++kk) {
      bf16x8 af[4], bfr[4];
#pragma unroll
      for (int mi = 0; mi < 4; ++mi)
        af[mi] = *(const bf16x8*)&lA[(wm * 64 + mi * 16 + l15) * 64 + kk * 32 + g * 8];
#pragma unroll
      for (int ni = 0; ni < 4; ++ni)
        bfr[ni] = *(const bf16x8*)&lB[(wn * 64 + ni * 16 + l15) * 64 + kk * 32 + g * 8];
#pragma unroll
      for (int mi = 0; mi < 4; ++mi)
#pragma unroll
        for (int ni = 0; ni < 4; ++ni)
          acc[mi][ni] = __builtin_amdgcn_mfma_f32_16x16x32_bf16(af[mi], bfr[ni], acc[mi][ni], 0, 0, 0);
    }
  }

#pragma unroll
  for (int mi = 0; mi < 4; ++mi)
#pragma unroll
    for (int ni = 0; ni < 4; ++ni) {
      const int col = blockIdx.y * 128 + wn * 64 + ni * 16 + l15;
      const float bcol = bias[col];
#pragma unroll
      for (int r = 0; r < 4; ++r) {
        const int row = blockIdx.x * 128 + wm * 64 + mi * 16 + g * 4 + r;
        const size_t o = (size_t)row * N + col;
        float val = acc[mi][ni][r] + bcol;
        if (EPI == 0) {
          outB[o] = f2bf(val);
        } else if (EPI == 1) {
          outF[o] = val + resid[o];
        } else {
          float ge = 0.5f * val * (1.0f + erff(val * 0.70710678118654752f));
          outB[o] = f2bf(ge);
        }
      }
    }
}

// ---------------- 128x64-tile GEMM (for skinny N: O-proj, FFN-down), EPI 1 ----------------
// out_f32 = v + bias + resid
__global__ __launch_bounds__(256, 2)
void gemm_n64(const unsigned short* __restrict__ A, const unsigned short* __restrict__ Bt,
              const float* __restrict__ bias, const float* __restrict__ resid,
              float* __restrict__ outF, int M, int N, int K) {
  __shared__ unsigned short lA[128 * 64];
  __shared__ unsigned short lB[64 * 64];
  const int t = threadIdx.x;
  const int lane = t & 63;
  const int w = t >> 6;
  const int wm = w >> 1, wn = w & 1;
  const int l15 = lane & 15, g = lane >> 4;

  const unsigned short* Ab = A + (size_t)blockIdx.x * 128 * K;
  const unsigned short* Bb = Bt + (size_t)blockIdx.y * 64 * K;

  f32x4 acc[4][2] = {};

  for (int k0 = 0; k0 < K; k0 += 64) {
    __syncthreads();
#pragma unroll
    for (int i = 0; i < 4; ++i) {
      int id = i * 256 + t;
      gload_lds16(Ab + (size_t)(id >> 3) * K + k0 + (id & 7) * 8, &lA[id * 8]);
    }
#pragma unroll
    for (int i = 0; i < 2; ++i) {
      int id = i * 256 + t;
      gload_lds16(Bb + (size_t)(id >> 3) * K + k0 + (id & 7) * 8, &lB[id * 8]);
    }
    __syncthreads();
#pragma unroll
    for (int kk = 0; kk < 2; ++kk) {
      bf16x8 af[4], bfr[2];
#pragma unroll
      for (int mi = 0; mi < 4; ++mi)
        af[mi] = *(const bf16x8*)&lA[(wm * 64 + mi * 16 + l15) * 64 + kk * 32 + g * 8];
#pragma unroll
      for (int ni = 0; ni < 2; ++ni)
        bfr[ni] = *(const bf16x8*)&lB[(wn * 32 + ni * 16 + l15) * 64 + kk * 32 + g * 8];
#pragma unroll
      for (int mi = 0; mi < 4; ++mi)
#pragma unroll
        for (int ni = 0; ni < 2; ++ni)
          acc[mi][ni] = __builtin_amdgcn_mfma_f32_16x16x32_bf16(af[mi], bfr[ni], acc[mi][ni], 0, 0, 0);
    }
  }

#pragma unroll
  for (int mi = 0; mi < 4; ++mi)
#pragma unroll
    for (int ni = 0; ni < 2; ++ni) {
      const int col = blockIdx.y * 64 + wn * 32 + ni * 16 + l15;
      const float bcol = bias[col];
#pragma unroll
      for (int r = 0; r < 4; ++r) {
        const int row = blockIdx.x * 128 + wm * 64 + mi * 16 + g * 4 + r;
        const size_t o = (size_t)row * N + col;
        outF[o] = acc[mi][ni][r] + bcol + resid[o];
      }
    }
}

// ---------------- flash attention v2 ----------------
// grid: (N/128, B*H), 256 threads = 4 waves, 32 q-rows per wave; KVBLK=64.
// K, V^T staged in LDS (double-buffered, global_load_lds, XOR-swizzled).
// Swapped QK^T: S^T = mfma(K_frag, Q_frag) -> lane holds P[k=4g+r][q=l15].
// PV: O^T = mfma_16x16x16(V^T_frag, P_frag).
__global__ __launch_bounds__(256, 2)
void attn_fwd(const unsigned short* __restrict__ Qh, const unsigned short* __restrict__ Kh,
              const unsigned short* __restrict__ VhT, unsigned short* __restrict__ ctx) {
  __shared__ unsigned short lK[2][64 * 64];
  __shared__ unsigned short lV[2][64 * 64];

  const int t = threadIdx.x, lane = t & 63, w = t >> 6;
  const int l15 = lane & 15, g = lane >> 4;
  const int bh = blockIdx.y, b = bh >> 4, h = bh & 15;
  const int qb0 = blockIdx.x * 128 + w * 32;

  const unsigned short* Qb = Qh + (size_t)b * N_ * C_ + h * HD_;
  const unsigned short* Kb = Kh + (size_t)b * N_ * C_ + h * HD_;
  const unsigned short* Vb = VhT + (size_t)bh * HD_ * N_;

  bf16x8 qf[2][2];
#pragma unroll
  for (int qi = 0; qi < 2; ++qi)
#pragma unroll
    for (int kk = 0; kk < 2; ++kk)
      qf[qi][kk] = *(const bf16x8*)(Qb + (size_t)(qb0 + qi * 16 + l15) * C_ + kk * 32 + g * 8);

  // stage: linear LDS dest, inverse-swizzled global source (rule #21)
  auto stageK = [&](int buf, int kb) {
#pragma unroll
    for (int i = 0; i < 2; ++i) {
      int o = (i * 256 + t) * 16;                 // tile byte offset
      int r = o >> 7;                             // row (key)
      int c = (o & 127) ^ ((r & 7) << 4);         // swizzled byte col
      gload_lds16(Kb + (size_t)(kb + r) * C_ + (c >> 1), &lK[buf][o >> 1]);
    }
  };
  auto stageV = [&](int buf, int kb) {
#pragma unroll
    for (int i = 0; i < 2; ++i) {
      int o = (i * 256 + t) * 16;
      int r = o >> 7;                             // row (d)
      int c = (o & 127) ^ ((r & 7) << 4);
      gload_lds16(Vb + (size_t)r * N_ + kb + (c >> 1), &lV[buf][o >> 1]);
    }
  };

  f32x4 od[4][2] = {};
  float mrun[2] = {-1e30f, -1e30f};
  float srun[2] = {0.f, 0.f};
  const float c1 = 0.18033688011112042f;  // 1/sqrt(64) * log2(e)
  const float DTHR = 8.0f / 0.18033688011112042f;

  stageK(0, 0);
  stageV(0, 0);
  __syncthreads();

  int cur = 0;
  for (int tile = 0; tile < N_ / 64; ++tile) {
    if (tile + 1 < N_ / 64) {
      stageK(cur ^ 1, (tile + 1) * 64);
      stageV(cur ^ 1, (tile + 1) * 64);
    }

    // QK^T on staged tile
    f32x4 st[4][2];
#pragma unroll
    for (int kf = 0; kf < 4; ++kf) {
      const int krow = kf * 16 + l15;
      const int sw = (krow & 7) << 4;
      const bf16x8 ka = *(const bf16x8*)&lK[cur][krow * 64 + ((( g * 16) ^ sw) >> 1)];
      const bf16x8 kc = *(const bf16x8*)&lK[cur][krow * 64 + (((64 + g * 16) ^ sw) >> 1)];
#pragma unroll
      for (int qi = 0; qi < 2; ++qi) {
        f32x4 z = {};
        z = __builtin_amdgcn_mfma_f32_16x16x32_bf16(ka, qf[qi][0], z, 0, 0, 0);
        z = __builtin_amdgcn_mfma_f32_16x16x32_bf16(kc, qf[qi][1], z, 0, 0, 0);
        st[kf][qi] = z;
      }
    }

    // online softmax with defer-max
    s16x4 pb[4][2];
#pragma unroll
    for (int qi = 0; qi < 2; ++qi) {
      float mx = st[0][qi][0];
#pragma unroll
      for (int r = 1; r < 4; ++r) mx = fmaxf(mx, st[0][qi][r]);
#pragma unroll
      for (int kf = 1; kf < 4; ++kf)
#pragma unroll
        for (int r = 0; r < 4; ++r) mx = fmaxf(mx, st[kf][qi][r]);
      mx = fmaxf(mx, __shfl_xor(mx, 16));
      mx = fmaxf(mx, __shfl_xor(mx, 32));
      if (__any(mx > mrun[qi] + DTHR)) {
        const float mn = fmaxf(mrun[qi], mx);
        const float sf = exp2f((mrun[qi] - mn) * c1);
        mrun[qi] = mn;
        srun[qi] *= sf;
#pragma unroll
        for (int di = 0; di < 4; ++di)
#pragma unroll
          for (int r = 0; r < 4; ++r) od[di][qi][r] *= sf;
      }
      const float mc = mrun[qi] * c1;
#pragma unroll
      for (int kf = 0; kf < 4; ++kf) {
        union { s16x4 v; __bf16 e[4]; } u;
#pragma unroll
        for (int r = 0; r < 4; ++r) {
          float pv = exp2f(st[kf][qi][r] * c1 - mc);
          srun[qi] += pv;
          u.e[r] = (__bf16)pv;
        }
        pb[kf][qi] = u.v;
      }
    }

    // PV from staged V^T
#pragma unroll
    for (int di = 0; di < 4; ++di) {
      const int vrow = di * 16 + l15;
      const int sw = (vrow & 7) << 4;
#pragma unroll
      for (int kf = 0; kf < 4; ++kf) {
        const s16x4 vt = *(const s16x4*)&lV[cur][vrow * 64 + (((kf * 32 + g * 8) ^ sw) >> 1)];
#pragma unroll
        for (int qi = 0; qi < 2; ++qi)
          od[di][qi] = __builtin_amdgcn_mfma_f32_16x16x16bf16_1k(vt, pb[kf][qi], od[di][qi], 0, 0, 0);
      }
    }

    __syncthreads();
    cur ^= 1;
  }

#pragma unroll
  for (int qi = 0; qi < 2; ++qi) {
    float s = srun[qi];
    s += __shfl_xor(s, 16);
    s += __shfl_xor(s, 32);
    float rinv = 1.0f / s;
    const int q = qb0 + qi * 16 + l15;
#pragma unroll
    for (int di = 0; di < 4; ++di)
#pragma unroll
      for (int r = 0; r < 4; ++r) {
        int d = di * 16 + g * 4 + r;
        ctx[((size_t)(b * N_ + q)) * C_ + h * HD_ + d] = f2bf(od[di][qi][r] * rinv);
      }
  }
}

// ---------------- LayerNorm: x f32 [BN, C] -> h bf16 ----------------
__global__ __launch_bounds__(256)
void ln_kernel(const float* __restrict__ x, const float* __restrict__ lw,
               const float* __restrict__ lb, unsigned short* __restrict__ h) {
  const int row = blockIdx.x;
  const int t = threadIdx.x;
  const float4 v = ((const float4*)(x + (size_t)row * C_))[t];
  float sum = v.x + v.y + v.z + v.w;
#pragma unroll
  for (int m = 1; m < 64; m <<= 1) sum += __shfl_xor(sum, m);
  __shared__ float red[8];
  if ((t & 63) == 0) red[t >> 6] = sum;
  __syncthreads();
  const float mu = (red[0] + red[1] + red[2] + red[3]) * (1.0f / C_);
  const float d0 = v.x - mu, d1 = v.y - mu, d2 = v.z - mu, d3 = v.w - mu;
  float sq = d0 * d0 + d1 * d1 + d2 * d2 + d3 * d3;
#pragma unroll
  for (int m = 1; m < 64; m <<= 1) sq += __shfl_xor(sq, m);
  if ((t & 63) == 0) red[4 + (t >> 6)] = sq;
  __syncthreads();
  const float var = (red[4] + red[5] + red[6] + red[7]) * (1.0f / C_);
  const float rstd = rsqrtf(var + 1e-5f);
  const float4 ww = ((const float4*)lw)[t];
  const float4 bb = ((const float4*)lb)[t];
  uint2 o;
  o.x = (unsigned)f2bf(d0 * rstd * ww.x + bb.x) | ((unsigned)f2bf(d1 * rstd * ww.y + bb.y) << 16);
  o.y = (unsigned)f2bf(d2 * rstd * ww.z + bb.z) | ((unsigned)f2bf(d3 * rstd * ww.w + bb.w) << 16);
  ((uint2*)(h + (size_t)row * C_))[t] = o;
}

extern "C" void kernel_launch(void* const* d_in, const int* in_sizes, int n_in,
                              void* d_out, int out_size, void* d_ws, size_t ws_size,
                              hipStream_t stream) {
  const float* q   = (const float*)d_in[0];
  const float* k   = (const float*)d_in[1];
  const float* v   = (const float*)d_in[2];
  const float* Wq  = (const float*)d_in[3];
  const float* bq  = (const float*)d_in[4];
  const float* Wk  = (const float*)d_in[5];
  const float* bk  = (const float*)d_in[6];
  const float* Wv  = (const float*)d_in[7];
  const float* bv  = (const float*)d_in[8];
  const float* Wo  = (const float*)d_in[9];
  const float* bo  = (const float*)d_in[10];
  const float* lnw = (const float*)d_in[11];
  const float* lnb = (const float*)d_in[12];
  const float* W1  = (const float*)d_in[13];
  const float* b1  = (const float*)d_in[14];
  const float* W2  = (const float*)d_in[15];
  const float* b2  = (const float*)d_in[16];
  float* out = (float*)d_out;

  char* ws = (char*)d_ws;
  const size_t MB = 1024 * 1024;
  if (ws_size < 120 * MB) return;
  unsigned short* qb   = (unsigned short*)(ws + 0 * MB);
  unsigned short* kb   = (unsigned short*)(ws + 8 * MB);
  unsigned short* vb   = (unsigned short*)(ws + 16 * MB);
  unsigned short* Wqt  = (unsigned short*)(ws + 24 * MB);
  unsigned short* Wkt  = (unsigned short*)(ws + 26 * MB);
  unsigned short* Wvt  = (unsigned short*)(ws + 28 * MB);
  unsigned short* Wot  = (unsigned short*)(ws + 30 * MB);
  unsigned short* W1t  = (unsigned short*)(ws + 32 * MB);
  unsigned short* W2t  = (unsigned short*)(ws + 36 * MB);
  unsigned short* Qh   = (unsigned short*)(ws + 40 * MB);
  unsigned short* Kh   = (unsigned short*)(ws + 48 * MB);
  unsigned short* Vh   = (unsigned short*)(ws + 56 * MB);
  unsigned short* VhT  = (unsigned short*)(ws + 64 * MB);
  unsigned short* ctx  = (unsigned short*)(ws + 72 * MB);
  float*          xf   = (float*)(ws + 80 * MB);
  unsigned short* hb   = (unsigned short*)(ws + 96 * MB);
  unsigned short* tbuf = (unsigned short*)(ws + 104 * MB);

  const int n8 = B_ * N_ * C_ / 8;
  cast3_bf16<<<dim3((n8 + 255) / 256, 1, 3), 256, 0, stream>>>(q, k, v, qb, kb, vb, n8);

  dim3 blk32(32, 8);
  wt_cast4<<<dim3(C_ / 32, C_ / 32, 4), blk32, 0, stream>>>(Wq, Wk, Wv, Wo, Wqt, Wkt, Wvt, Wot);
  wt_cast<<<dim3(FF_ / 32, C_ / 32), blk32, 0, stream>>>(W1, W1t, C_, FF_);
  wt_cast<<<dim3(C_ / 32, FF_ / 32), blk32, 0, stream>>>(W2, W2t, FF_, C_);

  gemm_qkv<<<dim3(B_ * N_ / 128, C_ / 128, 3), 256, 0, stream>>>(qb, kb, vb, Wqt, Wkt, Wvt,
                                                                 bq, bk, bv, Qh, Kh, Vh);

  vh_transpose<<<dim3(N_ / 32, HD_ / 32, B_ * H_), blk32, 0, stream>>>(Vh, VhT);
  attn_fwd<<<dim3(N_ / 128, B_ * H_), 256, 0, stream>>>(Qh, Kh, VhT, ctx);

  gemm_n64<<<dim3(B_ * N_ / 128, C_ / 64), 256, 0, stream>>>(ctx, Wot, bo, q, xf, B_ * N_, C_, C_);
  ln_kernel<<<dim3(B_ * N_), 256, 0, stream>>>(xf, lnw, lnb, hb);
  gemm_bt<2><<<dim3(B_ * N_ / 128, FF_ / 128), 256, 0, stream>>>(hb, W1t, b1, nullptr, nullptr, tbuf,
                                                                 B_ * N_, FF_, C_);
  gemm_n64<<<dim3(B_ * N_ / 128, C_ / 64), 256, 0, stream>>>(tbuf, W2t, b2, xf, out, B_ * N_, C_, FF_);
}

// Round 3
// 241.843 us; speedup vs baseline: 1.6092x; 1.0145x over previous
//
#include <hip/hip_runtime.h>

constexpr int B_ = 2, N_ = 2048, C_ = 1024, H_ = 16, HD_ = 64, FF_ = 2048;

typedef __attribute__((ext_vector_type(8))) __bf16 bf16x8;
typedef __attribute__((ext_vector_type(4))) float f32x4;
typedef __attribute__((ext_vector_type(4))) short s16x4;

__device__ __forceinline__ unsigned short f2bf(float f) {
  union { float f; unsigned int u; } v; v.f = f;
  unsigned int r = v.u + 0x7fffu + ((v.u >> 16) & 1u);
  return (unsigned short)(r >> 16);
}

__device__ __forceinline__ void gload_lds16(const unsigned short* g, unsigned short* l) {
  __builtin_amdgcn_global_load_lds((const __attribute__((address_space(1))) void*)g,
                                   (__attribute__((address_space(3))) void*)l, 16, 0, 0);
}

// ---------------- cast f32 -> bf16, z-fused over q,k,v ----------------
__global__ __launch_bounds__(256)
void cast3_bf16(const float* __restrict__ q, const float* __restrict__ k,
                const float* __restrict__ v, unsigned short* __restrict__ qo,
                unsigned short* __restrict__ ko, unsigned short* __restrict__ vo, int n8) {
  int i = blockIdx.x * 256 + threadIdx.x;
  if (i >= n8) return;
  const float* in = blockIdx.z == 0 ? q : (blockIdx.z == 1 ? k : v);
  unsigned short* out = blockIdx.z == 0 ? qo : (blockIdx.z == 1 ? ko : vo);
  const float4 a = ((const float4*)in)[2 * i];
  const float4 b = ((const float4*)in)[2 * i + 1];
  uint4 o;
  o.x = (unsigned)f2bf(a.x) | ((unsigned)f2bf(a.y) << 16);
  o.y = (unsigned)f2bf(a.z) | ((unsigned)f2bf(a.w) << 16);
  o.z = (unsigned)f2bf(b.x) | ((unsigned)f2bf(b.y) << 16);
  o.w = (unsigned)f2bf(b.z) | ((unsigned)f2bf(b.w) << 16);
  ((uint4*)out)[i] = o;
}

// ---------------- cast+transpose weights: W[K][N] f32 -> Wt[N][K] bf16 ----------------
__global__ __launch_bounds__(256)
void wt_cast(const float* __restrict__ W, unsigned short* __restrict__ Wt, int K, int N) {
  __shared__ unsigned short tile[32][33];
  const int tx = threadIdx.x, ty = threadIdx.y;
  const int n0 = blockIdx.x * 32, k0 = blockIdx.y * 32;
#pragma unroll
  for (int r = 0; r < 4; ++r)
    tile[ty + r * 8][tx] = f2bf(W[(size_t)(k0 + ty + r * 8) * N + n0 + tx]);
  __syncthreads();
#pragma unroll
  for (int r = 0; r < 4; ++r)
    Wt[(size_t)(n0 + ty + r * 8) * K + k0 + tx] = tile[tx][ty + r * 8];
}

// z-fused version for the four C x C weights
__global__ __launch_bounds__(256)
void wt_cast4(const float* __restrict__ Wa, const float* __restrict__ Wb,
              const float* __restrict__ Wc, const float* __restrict__ Wd,
              unsigned short* __restrict__ Oa, unsigned short* __restrict__ Ob,
              unsigned short* __restrict__ Oc, unsigned short* __restrict__ Od) {
  __shared__ unsigned short tile[32][33];
  const int z = blockIdx.z;
  const float* W = z == 0 ? Wa : (z == 1 ? Wb : (z == 2 ? Wc : Wd));
  unsigned short* Wt = z == 0 ? Oa : (z == 1 ? Ob : (z == 2 ? Oc : Od));
  const int tx = threadIdx.x, ty = threadIdx.y;
  const int n0 = blockIdx.x * 32, k0 = blockIdx.y * 32;
#pragma unroll
  for (int r = 0; r < 4; ++r)
    tile[ty + r * 8][tx] = f2bf(W[(size_t)(k0 + ty + r * 8) * C_ + n0 + tx]);
  __syncthreads();
#pragma unroll
  for (int r = 0; r < 4; ++r)
    Wt[(size_t)(n0 + ty + r * 8) * C_ + k0 + tx] = tile[tx][ty + r * 8];
}

// ---------------- Vh [B,N,H,HD] -> VhT [B,H,HD,N] (bf16) ----------------
__global__ __launch_bounds__(256)
void vh_transpose(const unsigned short* __restrict__ Vh, unsigned short* __restrict__ VhT) {
  __shared__ unsigned short tile[32][33];
  const int tx = threadIdx.x, ty = threadIdx.y;
  const int bh = blockIdx.z, b = bh >> 4, h = bh & 15;
  const int n0 = blockIdx.x * 32, d0 = blockIdx.y * 32;
#pragma unroll
  for (int r = 0; r < 4; ++r) {
    int n = n0 + ty + r * 8;
    tile[ty + r * 8][tx] = Vh[((size_t)(b * N_ + n)) * C_ + h * HD_ + d0 + tx];
  }
  __syncthreads();
#pragma unroll
  for (int r = 0; r < 4; ++r) {
    int d = d0 + ty + r * 8;
    VhT[((size_t)(bh * HD_ + d)) * N_ + n0 + tx] = tile[tx][ty + r * 8];
  }
}

// ---------------- 128x128 GEMM, z-fused QKV projections (out bf16 = v+bias) ----------------
__global__ __launch_bounds__(256, 2)
void gemm_qkv(const unsigned short* __restrict__ A0, const unsigned short* __restrict__ A1,
              const unsigned short* __restrict__ A2, const unsigned short* __restrict__ B0,
              const unsigned short* __restrict__ B1, const unsigned short* __restrict__ B2,
              const float* __restrict__ c0, const float* __restrict__ c1v,
              const float* __restrict__ c2, unsigned short* __restrict__ O0,
              unsigned short* __restrict__ O1, unsigned short* __restrict__ O2) {
  const int z = blockIdx.z;
  const unsigned short* A = z == 0 ? A0 : (z == 1 ? A1 : A2);
  const unsigned short* Bt = z == 0 ? B0 : (z == 1 ? B1 : B2);
  const float* bias = z == 0 ? c0 : (z == 1 ? c1v : c2);
  unsigned short* outB = z == 0 ? O0 : (z == 1 ? O1 : O2);
  const int K = C_, Nn = C_;

  __shared__ unsigned short lA[128 * 64];
  __shared__ unsigned short lB[128 * 64];
  const int t = threadIdx.x;
  const int lane = t & 63;
  const int w = t >> 6;
  const int wm = w >> 1, wn = w & 1;
  const int l15 = lane & 15, g = lane >> 4;

  const unsigned short* Ab = A + (size_t)blockIdx.x * 128 * K;
  const unsigned short* Bb = Bt + (size_t)blockIdx.y * 128 * K;

  f32x4 acc[4][4] = {};

  for (int k0 = 0; k0 < K; k0 += 64) {
    __syncthreads();
#pragma unroll
    for (int i = 0; i < 4; ++i) {
      int id = i * 256 + t;
      gload_lds16(Ab + (size_t)(id >> 3) * K + k0 + (id & 7) * 8, &lA[id * 8]);
    }
#pragma unroll
    for (int i = 0; i < 4; ++i) {
      int id = i * 256 + t;
      gload_lds16(Bb + (size_t)(id >> 3) * K + k0 + (id & 7) * 8, &lB[id * 8]);
    }
    __syncthreads();
#pragma unroll
    for (int kk = 0; kk < 2; ++kk) {
      bf16x8 af[4], bfr[4];
#pragma unroll
      for (int mi = 0; mi < 4; ++mi)
        af[mi] = *(const bf16x8*)&lA[(wm * 64 + mi * 16 + l15) * 64 + kk * 32 + g * 8];
#pragma unroll
      for (int ni = 0; ni < 4; ++ni)
        bfr[ni] = *(const bf16x8*)&lB[(wn * 64 + ni * 16 + l15) * 64 + kk * 32 + g * 8];
#pragma unroll
      for (int mi = 0; mi < 4; ++mi)
#pragma unroll
        for (int ni = 0; ni < 4; ++ni)
          acc[mi][ni] = __builtin_amdgcn_mfma_f32_16x16x32_bf16(af[mi], bfr[ni], acc[mi][ni], 0, 0, 0);
    }
  }

#pragma unroll
  for (int mi = 0; mi < 4; ++mi)
#pragma unroll
    for (int ni = 0; ni < 4; ++ni) {
      const int col = blockIdx.y * 128 + wn * 64 + ni * 16 + l15;
      const float bcol = bias[col];
#pragma unroll
      for (int r = 0; r < 4; ++r) {
        const int row = blockIdx.x * 128 + wm * 64 + mi * 16 + g * 4 + r;
        outB[(size_t)row * Nn + col] = f2bf(acc[mi][ni][r] + bcol);
      }
    }
}

// ---------------- 128x128 GEMM with epilogues (used for FFN-up, gelu) ----------------
template <int EPI>
__global__ __launch_bounds__(256, 2)
void gemm_bt(const unsigned short* __restrict__ A, const unsigned short* __restrict__ Bt,
             const float* __restrict__ bias, const float* __restrict__ resid,
             float* __restrict__ outF, unsigned short* __restrict__ outB,
             int M, int N, int K) {
  __shared__ unsigned short lA[128 * 64];
  __shared__ unsigned short lB[128 * 64];
  const int t = threadIdx.x;
  const int lane = t & 63;
  const int w = t >> 6;
  const int wm = w >> 1, wn = w & 1;
  const int l15 = lane & 15, g = lane >> 4;

  const unsigned short* Ab = A + (size_t)blockIdx.x * 128 * K;
  const unsigned short* Bb = Bt + (size_t)blockIdx.y * 128 * K;

  f32x4 acc[4][4] = {};

  for (int k0 = 0; k0 < K; k0 += 64) {
    __syncthreads();
#pragma unroll
    for (int i = 0; i < 4; ++i) {
      int id = i * 256 + t;
      gload_lds16(Ab + (size_t)(id >> 3) * K + k0 + (id & 7) * 8, &lA[id * 8]);
    }
#pragma unroll
    for (int i = 0; i < 4; ++i) {
      int id = i * 256 + t;
      gload_lds16(Bb + (size_t)(id >> 3) * K + k0 + (id & 7) * 8, &lB[id * 8]);
    }
    __syncthreads();
#pragma unroll
    for (int kk = 0; kk < 2; ++kk) {
      bf16x8 af[4], bfr[4];
#pragma unroll
      for (int mi = 0; mi < 4; ++mi)
        af[mi] = *(const bf16x8*)&lA[(wm * 64 + mi * 16 + l15) * 64 + kk * 32 + g * 8];
#pragma unroll
      for (int ni = 0; ni < 4; ++ni)
        bfr[ni] = *(const bf16x8*)&lB[(wn * 64 + ni * 16 + l15) * 64 + kk * 32 + g * 8];
#pragma unroll
      for (int mi = 0; mi < 4; ++mi)
#pragma unroll
        for (int ni = 0; ni < 4; ++ni)
          acc[mi][ni] = __builtin_amdgcn_mfma_f32_16x16x32_bf16(af[mi], bfr[ni], acc[mi][ni], 0, 0, 0);
    }
  }

#pragma unroll
  for (int mi = 0; mi < 4; ++mi)
#pragma unroll
    for (int ni = 0; ni < 4; ++ni) {
      const int col = blockIdx.y * 128 + wn * 64 + ni * 16 + l15;
      const float bcol = bias[col];
#pragma unroll
      for (int r = 0; r < 4; ++r) {
        const int row = blockIdx.x * 128 + wm * 64 + mi * 16 + g * 4 + r;
        const size_t o = (size_t)row * N + col;
        float val = acc[mi][ni][r] + bcol;
        if (EPI == 0) {
          outB[o] = f2bf(val);
        } else if (EPI == 1) {
          outF[o] = val + resid[o];
        } else {
          float ge = 0.5f * val * (1.0f + erff(val * 0.70710678118654752f));
          outB[o] = f2bf(ge);
        }
      }
    }
}

// ---------------- 128x64-tile GEMM (skinny N: O-proj, FFN-down), out f32 = v+bias+resid ----------------
__global__ __launch_bounds__(256, 2)
void gemm_n64(const unsigned short* __restrict__ A, const unsigned short* __restrict__ Bt,
              const float* __restrict__ bias, const float* __restrict__ resid,
              float* __restrict__ outF, int M, int N, int K) {
  __shared__ unsigned short lA[128 * 64];
  __shared__ unsigned short lB[64 * 64];
  const int t = threadIdx.x;
  const int lane = t & 63;
  const int w = t >> 6;
  const int wm = w >> 1, wn = w & 1;
  const int l15 = lane & 15, g = lane >> 4;

  const unsigned short* Ab = A + (size_t)blockIdx.x * 128 * K;
  const unsigned short* Bb = Bt + (size_t)blockIdx.y * 64 * K;

  f32x4 acc[4][2] = {};

  for (int k0 = 0; k0 < K; k0 += 64) {
    __syncthreads();
#pragma unroll
    for (int i = 0; i < 4; ++i) {
      int id = i * 256 + t;
      gload_lds16(Ab + (size_t)(id >> 3) * K + k0 + (id & 7) * 8, &lA[id * 8]);
    }
#pragma unroll
    for (int i = 0; i < 2; ++i) {
      int id = i * 256 + t;
      gload_lds16(Bb + (size_t)(id >> 3) * K + k0 + (id & 7) * 8, &lB[id * 8]);
    }
    __syncthreads();
#pragma unroll
    for (int kk = 0; kk < 2; ++kk) {
      bf16x8 af[4], bfr[2];
#pragma unroll
      for (int mi = 0; mi < 4; ++mi)
        af[mi] = *(const bf16x8*)&lA[(wm * 64 + mi * 16 + l15) * 64 + kk * 32 + g * 8];
#pragma unroll
      for (int ni = 0; ni < 2; ++ni)
        bfr[ni] = *(const bf16x8*)&lB[(wn * 32 + ni * 16 + l15) * 64 + kk * 32 + g * 8];
#pragma unroll
      for (int mi = 0; mi < 4; ++mi)
#pragma unroll
        for (int ni = 0; ni < 2; ++ni)
          acc[mi][ni] = __builtin_amdgcn_mfma_f32_16x16x32_bf16(af[mi], bfr[ni], acc[mi][ni], 0, 0, 0);
    }
  }

#pragma unroll
  for (int mi = 0; mi < 4; ++mi)
#pragma unroll
    for (int ni = 0; ni < 2; ++ni) {
      const int col = blockIdx.y * 64 + wn * 32 + ni * 16 + l15;
      const float bcol = bias[col];
#pragma unroll
      for (int r = 0; r < 4; ++r) {
        const int row = blockIdx.x * 128 + wm * 64 + mi * 16 + g * 4 + r;
        const size_t o = (size_t)row * N + col;
        outF[o] = acc[mi][ni][r] + bcol + resid[o];
      }
    }
}

// ---------------- flash attention v3 ----------------
// grid: (N/128, B*H), 512 threads = 8 waves, 16 q-rows per wave; KVBLK=64.
// K, V^T staged in LDS (double-buffered, global_load_lds, XOR-swizzled).
// Swapped QK^T: S^T = mfma(K_frag, Q_frag) -> lane holds P[k=4g+r][q=l15].
// PV: O^T = mfma_16x16x16(V^T_frag, P_frag).
__global__ __launch_bounds__(512, 4)
void attn_fwd(const unsigned short* __restrict__ Qh, const unsigned short* __restrict__ Kh,
              const unsigned short* __restrict__ VhT, unsigned short* __restrict__ ctx) {
  __shared__ unsigned short lK[2][64 * 64];
  __shared__ unsigned short lV[2][64 * 64];

  const int t = threadIdx.x, lane = t & 63, w = t >> 6;
  const int l15 = lane & 15, g = lane >> 4;
  const int bh = blockIdx.y, b = bh >> 4, h = bh & 15;
  const int qb0 = blockIdx.x * 128 + w * 16;

  const unsigned short* Qb = Qh + (size_t)b * N_ * C_ + h * HD_;
  const unsigned short* Kb = Kh + (size_t)b * N_ * C_ + h * HD_;
  const unsigned short* Vb = VhT + (size_t)bh * HD_ * N_;

  bf16x8 qf[2];
#pragma unroll
  for (int kk = 0; kk < 2; ++kk)
    qf[kk] = *(const bf16x8*)(Qb + (size_t)(qb0 + l15) * C_ + kk * 32 + g * 8);

  // stage: linear LDS dest, inverse-swizzled global source (rule #21); 512 thr -> 1 load each
  auto stageK = [&](int buf, int kb) {
    int o = t * 16;                             // tile byte offset
    int r = o >> 7;                             // row (key)
    int c = (o & 127) ^ ((r & 7) << 4);         // swizzled byte col
    gload_lds16(Kb + (size_t)(kb + r) * C_ + (c >> 1), &lK[buf][o >> 1]);
  };
  auto stageV = [&](int buf, int kb) {
    int o = t * 16;
    int r = o >> 7;                             // row (d)
    int c = (o & 127) ^ ((r & 7) << 4);
    gload_lds16(Vb + (size_t)r * N_ + kb + (c >> 1), &lV[buf][o >> 1]);
  };

  f32x4 od[4] = {};
  float mrun = -1e30f;
  float srun = 0.f;
  const float c1 = 0.18033688011112042f;  // 1/sqrt(64) * log2(e)
  const float DTHR = 8.0f / 0.18033688011112042f;

  stageK(0, 0);
  stageV(0, 0);
  __syncthreads();

  int cur = 0;
  for (int tile = 0; tile < N_ / 64; ++tile) {
    if (tile + 1 < N_ / 64) {
      stageK(cur ^ 1, (tile + 1) * 64);
      stageV(cur ^ 1, (tile + 1) * 64);
    }

    // QK^T on staged tile
    f32x4 st[4];
    __builtin_amdgcn_s_setprio(1);
#pragma unroll
    for (int kf = 0; kf < 4; ++kf) {
      const int krow = kf * 16 + l15;
      const int sw = (krow & 7) << 4;
      const bf16x8 ka = *(const bf16x8*)&lK[cur][krow * 64 + ((( g * 16) ^ sw) >> 1)];
      const bf16x8 kc = *(const bf16x8*)&lK[cur][krow * 64 + (((64 + g * 16) ^ sw) >> 1)];
      f32x4 z = {};
      z = __builtin_amdgcn_mfma_f32_16x16x32_bf16(ka, qf[0], z, 0, 0, 0);
      z = __builtin_amdgcn_mfma_f32_16x16x32_bf16(kc, qf[1], z, 0, 0, 0);
      st[kf] = z;
    }
    __builtin_amdgcn_s_setprio(0);

    // online softmax with defer-max
    float mx = st[0][0];
#pragma unroll
    for (int r = 1; r < 4; ++r) mx = fmaxf(mx, st[0][r]);
#pragma unroll
    for (int kf = 1; kf < 4; ++kf)
#pragma unroll
      for (int r = 0; r < 4; ++r) mx = fmaxf(mx, st[kf][r]);
    mx = fmaxf(mx, __shfl_xor(mx, 16));
    mx = fmaxf(mx, __shfl_xor(mx, 32));
    if (__any(mx > mrun + DTHR)) {
      const float mn = fmaxf(mrun, mx);
      const float sf = exp2f((mrun - mn) * c1);
      mrun = mn;
      srun *= sf;
#pragma unroll
      for (int di = 0; di < 4; ++di)
#pragma unroll
        for (int r = 0; r < 4; ++r) od[di][r] *= sf;
    }
    const float mc = mrun * c1;
    s16x4 pb[4];
#pragma unroll
    for (int kf = 0; kf < 4; ++kf) {
      union { s16x4 v; __bf16 e[4]; } u;
#pragma unroll
      for (int r = 0; r < 4; ++r) {
        float pv = exp2f(st[kf][r] * c1 - mc);
        srun += pv;
        u.e[r] = (__bf16)pv;
      }
      pb[kf] = u.v;
    }

    // PV from staged V^T
    __builtin_amdgcn_s_setprio(1);
#pragma unroll
    for (int di = 0; di < 4; ++di) {
      const int vrow = di * 16 + l15;
      const int sw = (vrow & 7) << 4;
#pragma unroll
      for (int kf = 0; kf < 4; ++kf) {
        const s16x4 vt = *(const s16x4*)&lV[cur][vrow * 64 + (((kf * 32 + g * 8) ^ sw) >> 1)];
        od[di] = __builtin_amdgcn_mfma_f32_16x16x16bf16_1k(vt, pb[kf], od[di], 0, 0, 0);
      }
    }
    __builtin_amdgcn_s_setprio(0);

    __syncthreads();
    cur ^= 1;
  }

  float s = srun;
  s += __shfl_xor(s, 16);
  s += __shfl_xor(s, 32);
  const float rinv = 1.0f / s;
  const int q = qb0 + l15;
  unsigned short* cp = ctx + ((size_t)(b * N_ + q)) * C_ + h * HD_;
#pragma unroll
  for (int di = 0; di < 4; ++di) {
    uint2 o;
    o.x = (unsigned)f2bf(od[di][0] * rinv) | ((unsigned)f2bf(od[di][1] * rinv) << 16);
    o.y = (unsigned)f2bf(od[di][2] * rinv) | ((unsigned)f2bf(od[di][3] * rinv) << 16);
    *(uint2*)(cp + di * 16 + g * 4) = o;
  }
}

// ---------------- LayerNorm: x f32 [BN, C] -> h bf16 ----------------
__global__ __launch_bounds__(256)
void ln_kernel(const float* __restrict__ x, const float* __restrict__ lw,
               const float* __restrict__ lb, unsigned short* __restrict__ h) {
  const int row = blockIdx.x;
  const int t = threadIdx.x;
  const float4 v = ((const float4*)(x + (size_t)row * C_))[t];
  float sum = v.x + v.y + v.z + v.w;
#pragma unroll
  for (int m = 1; m < 64; m <<= 1) sum += __shfl_xor(sum, m);
  __shared__ float red[8];
  if ((t & 63) == 0) red[t >> 6] = sum;
  __syncthreads();
  const float mu = (red[0] + red[1] + red[2] + red[3]) * (1.0f / C_);
  const float d0 = v.x - mu, d1 = v.y - mu, d2 = v.z - mu, d3 = v.w - mu;
  float sq = d0 * d0 + d1 * d1 + d2 * d2 + d3 * d3;
#pragma unroll
  for (int m = 1; m < 64; m <<= 1) sq += __shfl_xor(sq, m);
  if ((t & 63) == 0) red[4 + (t >> 6)] = sq;
  __syncthreads();
  const float var = (red[4] + red[5] + red[6] + red[7]) * (1.0f / C_);
  const float rstd = rsqrtf(var + 1e-5f);
  const float4 ww = ((const float4*)lw)[t];
  const float4 bb = ((const float4*)lb)[t];
  uint2 o;
  o.x = (unsigned)f2bf(d0 * rstd * ww.x + bb.x) | ((unsigned)f2bf(d1 * rstd * ww.y + bb.y) << 16);
  o.y = (unsigned)f2bf(d2 * rstd * ww.z + bb.z) | ((unsigned)f2bf(d3 * rstd * ww.w + bb.w) << 16);
  ((uint2*)(h + (size_t)row * C_))[t] = o;
}

extern "C" void kernel_launch(void* const* d_in, const int* in_sizes, int n_in,
                              void* d_out, int out_size, void* d_ws, size_t ws_size,
                              hipStream_t stream) {
  const float* q   = (const float*)d_in[0];
  const float* k   = (const float*)d_in[1];
  const float* v   = (const float*)d_in[2];
  const float* Wq  = (const float*)d_in[3];
  const float* bq  = (const float*)d_in[4];
  const float* Wk  = (const float*)d_in[5];
  const float* bk  = (const float*)d_in[6];
  const float* Wv  = (const float*)d_in[7];
  const float* bv  = (const float*)d_in[8];
  const float* Wo  = (const float*)d_in[9];
  const float* bo  = (const float*)d_in[10];
  const float* lnw = (const float*)d_in[11];
  const float* lnb = (const float*)d_in[12];
  const float* W1  = (const float*)d_in[13];
  const float* b1  = (const float*)d_in[14];
  const float* W2  = (const float*)d_in[15];
  const float* b2  = (const float*)d_in[16];
  float* out = (float*)d_out;

  char* ws = (char*)d_ws;
  const size_t MB = 1024 * 1024;
  if (ws_size < 120 * MB) return;
  unsigned short* qb   = (unsigned short*)(ws + 0 * MB);
  unsigned short* kb   = (unsigned short*)(ws + 8 * MB);
  unsigned short* vb   = (unsigned short*)(ws + 16 * MB);
  unsigned short* Wqt  = (unsigned short*)(ws + 24 * MB);
  unsigned short* Wkt  = (unsigned short*)(ws + 26 * MB);
  unsigned short* Wvt  = (unsigned short*)(ws + 28 * MB);
  unsigned short* Wot  = (unsigned short*)(ws + 30 * MB);
  unsigned short* W1t  = (unsigned short*)(ws + 32 * MB);
  unsigned short* W2t  = (unsigned short*)(ws + 36 * MB);
  unsigned short* Qh   = (unsigned short*)(ws + 40 * MB);
  unsigned short* Kh   = (unsigned short*)(ws + 48 * MB);
  unsigned short* Vh   = (unsigned short*)(ws + 56 * MB);
  unsigned short* VhT  = (unsigned short*)(ws + 64 * MB);
  unsigned short* ctx  = (unsigned short*)(ws + 72 * MB);
  float*          xf   = (float*)(ws + 80 * MB);
  unsigned short* hb   = (unsigned short*)(ws + 96 * MB);
  unsigned short* tbuf = (unsigned short*)(ws + 104 * MB);

  const int n8 = B_ * N_ * C_ / 8;
  cast3_bf16<<<dim3((n8 + 255) / 256, 1, 3), 256, 0, stream>>>(q, k, v, qb, kb, vb, n8);

  dim3 blk32(32, 8);
  wt_cast4<<<dim3(C_ / 32, C_ / 32, 4), blk32, 0, stream>>>(Wq, Wk, Wv, Wo, Wqt, Wkt, Wvt, Wot);
  wt_cast<<<dim3(FF_ / 32, C_ / 32), blk32, 0, stream>>>(W1, W1t, C_, FF_);
  wt_cast<<<dim3(C_ / 32, FF_ / 32), blk32, 0, stream>>>(W2, W2t, FF_, C_);

  gemm_qkv<<<dim3(B_ * N_ / 128, C_ / 128, 3), 256, 0, stream>>>(qb, kb, vb, Wqt, Wkt, Wvt,
                                                                 bq, bk, bv, Qh, Kh, Vh);

  vh_transpose<<<dim3(N_ / 32, HD_ / 32, B_ * H_), blk32, 0, stream>>>(Vh, VhT);
  attn_fwd<<<dim3(N_ / 128, B_ * H_), 512, 0, stream>>>(Qh, Kh, VhT, ctx);

  gemm_n64<<<dim3(B_ * N_ / 128, C_ / 64), 256, 0, stream>>>(ctx, Wot, bo, q, xf, B_ * N_, C_, C_);
  ln_kernel<<<dim3(B_ * N_), 256, 0, stream>>>(xf, lnw, lnb, hb);
  gemm_bt<2><<<dim3(B_ * N_ / 128, FF_ / 128), 256, 0, stream>>>(hb, W1t, b1, nullptr, nullptr, tbuf,
                                                                 B_ * N_, FF_, C_);
  gemm_n64<<<dim3(B_ * N_ / 128, C_ / 64), 256, 0, stream>>>(tbuf, W2t, b2, xf, out, B_ * N_, C_, FF_);
}